// Round 8
// baseline (680.527 us; speedup 1.0000x reference)
//
#include <hip/hip_runtime.h>

// MHA forward: B=2, T=2048, DIM=1024, NH=16, HD=64
// ONE kernel, 768 persistent blocks (guaranteed co-resident: LB(256,4) => 4
// blocks/CU x 256 CU = 1024 >= 768), software grid barrier (device-scope
// atomics in zeroed ws; init kernel zeroes it first). Phases:
//  P0 prep (fp32->bf16 X, transposed W)   P1 qkv GEMM+RoPE
//  P2 flash attn (deep-first work-stealing, S^T/packed-P b64 writes)
//  P3 proj GEMM (blocks 0..255)

typedef float  f32x4   __attribute__((ext_vector_type(4)));
typedef __bf16 bf16x8  __attribute__((ext_vector_type(8)));
typedef short  short8  __attribute__((ext_vector_type(8)));
typedef short  short4v __attribute__((ext_vector_type(4)));

#define Tt 2048
#define NBLK 768u

__device__ __forceinline__ short f2bf(float f) {            // RNE
    unsigned u = __builtin_bit_cast(unsigned, f);
    u += 0x7fffu + ((u >> 16) & 1u);
    return (short)(u >> 16);
}
__device__ __forceinline__ short f2bf_t(float f) {          // truncate (P only)
    return (short)(__builtin_bit_cast(unsigned, f) >> 16);
}
__device__ __forceinline__ f32x4 mfma16(short8 a, short8 b, f32x4 c) {
    return __builtin_amdgcn_mfma_f32_16x16x32_bf16(
        __builtin_bit_cast(bf16x8, a), __builtin_bit_cast(bf16x8, b), c, 0, 0, 0);
}
__device__ __forceinline__ void gl_lds16(const void* g, void* l) {
    __builtin_amdgcn_global_load_lds(
        (const __attribute__((address_space(1))) unsigned int*)g,
        (__attribute__((address_space(3))) unsigned int*)l, 16, 0, 0);
}

// software grid barrier: one-shot counter per sync point, device scope.
__device__ __forceinline__ void gbar(unsigned* B) {
    __syncthreads();
    if (threadIdx.x == 0) {
        __threadfence();                                    // publish phase writes
        __hip_atomic_fetch_add(B, 1u, __ATOMIC_RELEASE, __HIP_MEMORY_SCOPE_AGENT);
        while (__hip_atomic_load(B, __ATOMIC_ACQUIRE, __HIP_MEMORY_SCOPE_AGENT) < NBLK)
            __builtin_amdgcn_s_sleep(2);
    }
    __syncthreads();
}

__global__ void zinit(unsigned* p) {
    if (threadIdx.x < 8) p[threadIdx.x] = 0u;
}

// 128x128 GEMM tile, BK=32, both operands staged via global_load_lds w16 with
// 16B-chunk XOR swizzle. Uses: tid, wv, lane, g, l16, wr, wc, bm, bn, As, Bs, acc.
#define GEMM_BK32_LOOP(Aptr, Bptr)                                                \
    for (int k0 = 0; k0 < 1024; k0 += 32) {                                       \
        _Pragma("unroll")                                                         \
        for (int i = 0; i < 2; i++) {                                             \
            int p = tid + i * 256;                                                \
            int row = p >> 2, c = p & 3, gcs = (c ^ (row & 3)) * 8;               \
            gl_lds16(Aptr + (size_t)(bm * 128 + row) * 1024 + k0 + gcs,           \
                     &As[row][c * 8]);                                            \
        }                                                                         \
        _Pragma("unroll")                                                         \
        for (int i = 0; i < 2; i++) {                                             \
            int p = tid + i * 256;                                                \
            int row = p >> 2, c = p & 3, gcs = (c ^ (row & 3)) * 8;               \
            gl_lds16(Bptr + (size_t)(bn * 128 + row) * 1024 + k0 + gcs,           \
                     &Bs[row][c * 8]);                                            \
        }                                                                         \
        __syncthreads();                                                          \
        short8 af[4], bfr[4];                                                     \
        _Pragma("unroll")                                                         \
        for (int mt = 0; mt < 4; mt++)                                            \
            af[mt] = *(const short8*)&As[wr * 64 + mt * 16 + l16]                 \
                                       [(g ^ (l16 & 3)) * 8];                     \
        _Pragma("unroll")                                                         \
        for (int nt = 0; nt < 4; nt++)                                            \
            bfr[nt] = *(const short8*)&Bs[wc * 64 + nt * 16 + l16]                \
                                        [(g ^ (l16 & 3)) * 8];                    \
        _Pragma("unroll")                                                         \
        for (int mt = 0; mt < 4; mt++)                                            \
            _Pragma("unroll")                                                     \
            for (int nt = 0; nt < 4; nt++)                                        \
                acc[mt][nt] = mfma16(af[mt], bfr[nt], acc[mt][nt]);               \
        __syncthreads();                                                          \
    }

__global__ __launch_bounds__(256, 4) void fused(
    const float* __restrict__ X,  const float* __restrict__ Sn,
    const float* __restrict__ Cs, const float* __restrict__ Wq,
    const float* __restrict__ Wp, float* __restrict__ Out,
    short* __restrict__ Qg, short* __restrict__ Kg, short* __restrict__ Vg,
    short* __restrict__ Yg, short* __restrict__ Xb,
    short* __restrict__ Wqt, short* __restrict__ Wpt,
    unsigned* __restrict__ sync)        // sync[0..2]=barriers, sync[3]=steal ctr
{
    __shared__ __align__(16) char smem[25600];
    __shared__ unsigned su;
    const int blk = blockIdx.x, tid = threadIdx.x;
    const int wv = tid >> 6, lane = tid & 63, g = lane >> 4, l16 = lane & 15;

    // ---------------- P0: prep (3072 units, 4 per block) -------------------
    {
        float (*L)[65] = (float(*)[65])smem;
        for (int u = blk; u < 3072; u += 768) {
            if (u < 2048) {                          // X fp32 -> bf16
                size_t i = ((size_t)u * 256 + tid) * 8;
                float4 a = *(const float4*)(X + i);
                float4 b = *(const float4*)(X + i + 4);
                short8 s;
                s[0] = f2bf(a.x); s[1] = f2bf(a.y); s[2] = f2bf(a.z); s[3] = f2bf(a.w);
                s[4] = f2bf(b.x); s[5] = f2bf(b.y); s[6] = f2bf(b.z); s[7] = f2bf(b.w);
                *(short8*)(Xb + i) = s;
            } else {                                 // W transpose fp32 -> bf16
                const float* W; short* Wt; int N, id2;
                if (u < 2816) { W = Wq; Wt = Wqt; N = 3072; id2 = u - 2048; }
                else          { W = Wp; Wt = Wpt; N = 1024; id2 = u - 2816; }
                const int kb = (id2 & 15) * 64, nb = (id2 >> 4) * 64;
                __syncthreads();                     // protect L reuse
#pragma unroll
                for (int it = 0; it < 4; it++) {
                    int kk = it * 16 + (tid >> 4), c = (tid & 15) * 4;
                    float4 v = *(const float4*)(W + (size_t)(kb + kk) * N + nb + c);
                    L[c + 0][kk] = v.x; L[c + 1][kk] = v.y;
                    L[c + 2][kk] = v.z; L[c + 3][kk] = v.w;
                }
                __syncthreads();
#pragma unroll
                for (int it = 0; it < 2; it++) {
                    int n = it * 32 + (tid >> 3), ks = (tid & 7) * 8;
                    short8 s;
#pragma unroll
                    for (int j = 0; j < 8; j++) s[j] = f2bf(L[n][ks + j]);
                    *(short8*)(Wt + (size_t)(nb + n) * 1024 + kb + ks) = s;
                }
            }
        }
    }
    gbar(&sync[0]);

    // ---------------- P1: qkv GEMM + RoPE (768 tiles, 1 per block) ---------
    {
        short (*As)[32] = (short(*)[32])smem;
        short (*Bs)[32] = (short(*)[32])(smem + 8192);
        const int bm = blk & 31, bn = blk >> 5;
        const int wr = wv >> 1, wc = wv & 1;
        f32x4 acc[4][4];
#pragma unroll
        for (int i = 0; i < 4; i++)
#pragma unroll
            for (int j = 0; j < 4; j++) acc[i][j] = (f32x4){0.f, 0.f, 0.f, 0.f};

        GEMM_BK32_LOOP(Xb, Wqt)

#pragma unroll
        for (int mt = 0; mt < 4; mt++)
#pragma unroll
            for (int nt = 0; nt < 4; nt++)
#pragma unroll
                for (int r = 0; r < 4; r++) {
                    int m = bm * 128 + wr * 64 + mt * 16 + g * 4 + r;
                    int n = bn * 128 + wc * 64 + nt * 16 + l16;
                    float val = acc[mt][nt][r];
                    float partner = __shfl_xor(val, 1, 64);
                    int b = m >> 11, t = m & 2047;
                    int sec = n >> 10, nn = n & 1023;
                    int h = nn >> 6, d = nn & 63;
                    if (sec == 2) {
                        Vg[(((size_t)(b * 16 + h) * 64 + d) << 11) + t] = f2bf(val);
                    } else {
                        float sv = Sn[t * 64 + d], cv = Cs[t * 64 + d];
                        float ro = (d & 1) ? fmaf(val, cv, partner * sv)
                                           : fmaf(val, cv, -partner * sv);
                        short* dst = (sec == 0) ? Qg : Kg;
                        dst[(((size_t)(b * 16 + h) << 11) + t) * 64 + d] = f2bf(ro);
                    }
                }
    }
    gbar(&sync[1]);

    // ---------------- P2: attn (1024 units, deep-first work-stealing) ------
    {
        short (*Ks)[64] = (short(*)[64])smem;               //  8 KB
        short (*Vs)[64] = (short(*)[64])(smem + 8192);      //  8 KB
        short* Plw = (short*)(smem + 16384) + wv * 16 * 72; //  4 x 16x72 = 9 KB
        const int rj = lane >> 3, cc = lane & 7, gc = cc ^ rj;
        const int sw = l16 & 7;
        short8 ones;
#pragma unroll
        for (int j = 0; j < 8; j++) ones[j] = (short)0x3F80;    // bf16 1.0

        for (;;) {
            __syncthreads();                       // su + LDS reuse guard
            if (tid == 0)
                su = __hip_atomic_fetch_add(&sync[3], 1u, __ATOMIC_RELAXED,
                                            __HIP_MEMORY_SCOPE_AGENT);
            __syncthreads();
            unsigned u = su;
            if (u >= 1024u) break;
            const int bh = (int)(u & 31u);
            const int qi = 31 - (int)(u >> 5);     // deep tiles first
            const short* Qb = Qg + (size_t)bh * Tt * 64;
            const short* Kb = Kg + (size_t)bh * Tt * 64;
            const short* Vb = Vg + (size_t)bh * 64 * Tt;
            const int b = bh >> 4, h = bh & 15;
            const int q0w = qi * 64 + wv * 16;

            short8 qf[2];
#pragma unroll
            for (int ss = 0; ss < 2; ss++)
                qf[ss] = *(const short8*)(Qb + (size_t)(q0w + l16) * 64 + ss * 32 + g * 8);

            f32x4 o[4], lacc = (f32x4){0.f, 0.f, 0.f, 0.f};
#pragma unroll
            for (int nt = 0; nt < 4; nt++) o[nt] = (f32x4){0.f, 0.f, 0.f, 0.f};

            const int nsteps = qi + 1;
            short8 kp[2], vp[2];
            auto preload = [&](int s) {
#pragma unroll
                for (int j = 0; j < 2; j++) {
                    int row = wv * 16 + j * 8 + rj;
                    kp[j] = *(const short8*)(Kb + (size_t)(s * 64 + row) * 64 + gc * 8);
                    vp[j] = *(const short8*)(Vb + (size_t)row * Tt + s * 64 + gc * 8);
                }
            };
            auto commit = [&]() {
#pragma unroll
                for (int j = 0; j < 2; j++) {
                    int row = wv * 16 + j * 8 + rj;
                    *(short8*)&Ks[row][cc << 3] = kp[j];
                    *(short8*)&Vs[row][cc << 3] = vp[j];
                }
            };

            preload(0); commit();
            __syncthreads();

            for (int s = 0; s < nsteps; ++s) {
                if (s + 1 < nsteps) preload(s + 1);
                const int k0 = s * 64;
                const bool diag = (s == qi);
                // S^T = K·Q^T (A=kf, B=qf): D row = key (g*4+r in tile t), col = q (l16)
#pragma unroll
                for (int t = 0; t < 4; t++) {
                    f32x4 S = (f32x4){0.f, 0.f, 0.f, 0.f};
#pragma unroll
                    for (int ss = 0; ss < 2; ss++) {
                        short8 kf = *(const short8*)&Ks[t * 16 + l16][((ss * 4 + g) ^ sw) << 3];
                        S = mfma16(kf, qf[ss], S);
                    }
                    short4v pk;
#pragma unroll
                    for (int r = 0; r < 4; r++) {
                        float e = exp2f(fmaf(S[r], 0.18033688f, -14.4269504f));
                        if (diag && (k0 + t * 16 + g * 4 + r > q0w + l16)) e = 0.f;
                        pk[r] = f2bf_t(e);
                    }
                    // P stored [q][key] (key 4-packed): single b64 write
                    *(short4v*)&Plw[l16 * 72 + t * 16 + g * 4] = pk;
                }
                asm volatile("" ::: "memory");     // per-wave DS ordering
                short8 pf[2];
#pragma unroll
                for (int ks = 0; ks < 2; ks++)
                    pf[ks] = *(const short8*)&Plw[l16 * 72 + ks * 32 + g * 8];
#pragma unroll
                for (int ks = 0; ks < 2; ks++) {
                    lacc = mfma16(pf[ks], ones, lacc);        // row-sum on MFMA
#pragma unroll
                    for (int nt = 0; nt < 4; nt++) {
                        short8 vf = *(const short8*)&Vs[nt * 16 + l16][((ks * 4 + g) ^ sw) << 3];
                        o[nt] = mfma16(pf[ks], vf, o[nt]);
                    }
                }
                __syncthreads();                   // compute done
                if (s + 1 < nsteps) { commit(); __syncthreads(); }
            }

            float inv[4];
#pragma unroll
            for (int r = 0; r < 4; r++) inv[r] = 1.0f / lacc[r];
#pragma unroll
            for (int nt = 0; nt < 4; nt++)
#pragma unroll
                for (int r = 0; r < 4; r++) {
                    int qq = q0w + g * 4 + r, d = nt * 16 + l16;
                    Yg[((size_t)(b * Tt + qq)) * 1024 + h * 64 + d] =
                        f2bf(o[nt][r] * inv[r]);
                }
        }
    }
    gbar(&sync[2]);

    // ---------------- P3: proj GEMM (256 tiles on blocks 0..255) -----------
    if (blk < 256) {
        short (*As)[32] = (short(*)[32])smem;
        short (*Bs)[32] = (short(*)[32])(smem + 8192);
        const int bm = blk & 31, bn = blk >> 5;
        const int wr = wv >> 1, wc = wv & 1;
        f32x4 acc[4][4];
#pragma unroll
        for (int i = 0; i < 4; i++)
#pragma unroll
            for (int j = 0; j < 4; j++) acc[i][j] = (f32x4){0.f, 0.f, 0.f, 0.f};

        GEMM_BK32_LOOP(Yg, Wpt)

#pragma unroll
        for (int mt = 0; mt < 4; mt++)
#pragma unroll
            for (int nt = 0; nt < 4; nt++)
#pragma unroll
                for (int r = 0; r < 4; r++) {
                    int m = bm * 128 + wr * 64 + mt * 16 + g * 4 + r;
                    int n = bn * 128 + wc * 64 + nt * 16 + l16;
                    Out[(size_t)m * 1024 + n] = acc[mt][nt][r];
                }
    }
}

// ---------------------------------------------------------------------------
extern "C" void kernel_launch(void* const* d_in, const int* in_sizes, int n_in,
                              void* d_out, int out_size, void* d_ws, size_t ws_size,
                              hipStream_t stream)
{
    const float* x     = (const float*)d_in[0];
    const float* sn    = (const float*)d_in[1];
    const float* cs    = (const float*)d_in[2];
    const float* wqkv  = (const float*)d_in[3];
    const float* wproj = (const float*)d_in[4];
    float* out = (float*)d_out;

    char* ws = (char*)d_ws;
    const size_t MB = 1024 * 1024;
    short* q    = (short*)(ws);            // 8 MB
    short* k    = (short*)(ws + 8  * MB);  // 8 MB
    short* vt   = (short*)(ws + 16 * MB);  // 8 MB
    short* y    = (short*)(ws + 24 * MB);  // 8 MB
    short* xb   = (short*)(ws + 32 * MB);  // 8 MB
    short* wqt  = (short*)(ws + 40 * MB);  // 6 MB
    short* wpt  = (short*)(ws + 46 * MB);  // 2 MB
    unsigned* sy = (unsigned*)(ws + 48 * MB);

    zinit<<<1, 64, 0, stream>>>(sy);
    fused<<<768, 256, 0, stream>>>(x, sn, cs, wqkv, wproj, out,
                                   q, k, vt, y, xb, wqt, wpt, sy);
}